// Round 14
// baseline (283.243 us; speedup 1.0000x reference)
//
#include <hip/hip_runtime.h>
#include <hip/hip_bf16.h>
#include <stdint.h>

// out[b, n] = sum_k weight[b, perm(k)] * fc_w[n, k] + fc_b[n]
// ROUND-14: 3-barrier K-tile schedule (from r13's measured 4-barrier, 209us,
// MfmaUtil 60.4%). Changes vs r13:
//  - BOTH A-half stages issue in P1-serial (P2 barrier dropped)
//  - bH drain = mid-cluster lgkm0 between QUAD00 and QUAD01
//  - STAGE B0(t+2) moved to post-P3-barrier (pre-barrier would formally race
//    with another wave's undrained bL-prefetch in the 3-barrier layout)
// Hazard trace:
//  WAR A(t+1)@P1 into nxt: any wave at t.P1 passed t-1.P4 barrier, reached
//    only after its own t-1.P3 lgkm0 drained its aHi reads of nxt. OK.
//  WAR B0(t+2) post-P3-bar into cur bL: bL-prefetch reads (issued t-1.P4
//    cluster) drained at each wave's t.P1 lgkm0 < its P3-barrier arrival. OK.
//  WAR B1(t+2)@P4-serial into cur bH: bH reads drained at mid-cluster lgkm0
//    < P3-barrier arrival of every wave. OK.
//  RAW: A(t+1)+B(t+1) drained at t.P4 vmcnt(4)+barrier before t+1 reads;
//    B(t+2) drained at t+1.P4. Ledger: enter 4, P1 +4=8, P3 +2=10, P4 +2=12,
//    vmcnt(4) leaves B(t+2)x4. Tail: 126 VMW0 (8 in flight), 127 none.

using f32x4   = __attribute__((ext_vector_type(4))) float;
using bf16x8  = __attribute__((ext_vector_type(8))) __bf16;
using ushort8 = __attribute__((ext_vector_type(8))) unsigned short;

#define B_ROWS 8192
#define K_TOT  8192
#define N_OUT  2048
#define BK     64
#define NT     (K_TOT / BK)  // 128 K-tiles

__device__ __forceinline__ unsigned short f2bf(float f) {
  union { float f; unsigned int u; } v;
  v.f = f;
  unsigned int r = v.u + 0x7FFFu + ((v.u >> 16) & 1u);  // RNE
  return (unsigned short)(r >> 16);
}

__device__ __forceinline__ int perm_src(int r, int s1, int s2) {
  int mid = s1 ? 1 : 2;
  return (r == 0) ? 0
       : (r == 1) ? (s1 ? 2 : 1)
       : (r == 2) ? (s2 ? 3 : mid)
                  : (s2 ? mid : 3);
}

// -------- prep (merged): permute+convert weight; convert fc_w --------
__global__ __launch_bounds__(256) void k_prep(
    const float* __restrict__ w, const int* __restrict__ s1v,
    const int* __restrict__ s2v, const float* __restrict__ fw,
    unsigned short* __restrict__ xbf, unsigned short* __restrict__ wbf) {
  const int blk = blockIdx.x;
  const float* src;
  unsigned short* dst;
  if (blk < B_ROWS * 4) {
    const int b = blk >> 2, r = blk & 3;
    const int s1 = s1v[b] != 0, s2 = s2v[b] != 0;
    const int pr = perm_src(r, s1, s2);
    src = w + (size_t)b * K_TOT + (size_t)pr * 2048 + threadIdx.x * 8;
    dst = xbf + (size_t)b * K_TOT + (size_t)r * 2048 + threadIdx.x * 8;
  } else {
    const size_t base = ((size_t)(blk - B_ROWS * 4) * 256 + threadIdx.x) * 8;
    src = fw + base;
    dst = wbf + base;
  }
  f32x4 v0 = *(const f32x4*)src;
  f32x4 v1 = *(const f32x4*)(src + 4);
  ushort8 o;
#pragma unroll
  for (int j = 0; j < 4; ++j) o[j] = f2bf(v0[j]);
#pragma unroll
  for (int j = 0; j < 4; ++j) o[4 + j] = f2bf(v1[j]);
  *(ushort8*)dst = o;
}

// -------- GEMM --------
__device__ __forceinline__ void gload16(const unsigned short* g,
                                        const unsigned short* l) {
  __builtin_amdgcn_global_load_lds(
      (__attribute__((address_space(1))) void*)(uintptr_t)(const void*)g,
      (__attribute__((address_space(3))) void*)(unsigned int)(uintptr_t)(const void*)l,
      16, 0, 0);
}

#define VMW4 asm volatile("s_waitcnt vmcnt(4)" ::: "memory")
#define VMW0 asm volatile("s_waitcnt vmcnt(0)" ::: "memory")
#define VMWN ((void)0)
#define SBAR asm volatile("s_barrier" ::: "memory")
#define LGKM0_FENCE do { \
    asm volatile("s_waitcnt lgkmcnt(0)" ::: "memory"); \
    __builtin_amdgcn_sched_barrier(0); } while (0)

#define LDA(BU, MH, M, KKI) \
  (*(const bf16x8*)(smb + (BU)*65536 + aBase + ((MH)*64 + (M)*16)*128 + colsw[KKI]))
#define LDB(BU, NH, N, KKI) \
  (*(const bf16x8*)(smb + (BU)*65536 + 32768 + bBase + ((NH)*32 + (N)*16)*128 + colsw[KKI]))

// one half-tile (128 rows x 64 cols) = 2 global_load_lds x 512 threads
#define STAGE(BU, OPL, GOP, H, T) do { \
  gload16((GOP) + (size_t)((H)*128 + row0) * K_TOT + (size_t)(T)*BK + sl0, \
          smu + (BU)*32768 + (OPL) + (H)*8192 + tid*8); \
  gload16((GOP) + (size_t)((H)*128 + row1) * K_TOT + (size_t)(T)*BK + sl1, \
          smu + (BU)*32768 + (OPL) + (H)*8192 + 4096 + tid*8); \
} while (0)

#define QUAD(MH, NH, B0A, B1A) do { \
  _Pragma("unroll") for (int m_ = 0; m_ < 4; ++m_) \
    _Pragma("unroll") for (int n_ = 0; n_ < 2; ++n_) { \
      acc[(MH)*4+m_][(NH)*2+n_] = __builtin_amdgcn_mfma_f32_16x16x32_bf16( \
          aR0[m_], B0A[n_], acc[(MH)*4+m_][(NH)*2+n_], 0, 0, 0); \
      acc[(MH)*4+m_][(NH)*2+n_] = __builtin_amdgcn_mfma_f32_16x16x32_bf16( \
          aR1[m_], B1A[n_], acc[(MH)*4+m_][(NH)*2+n_], 0, 0, 0); \
    } \
} while (0)

// Per K-tile, 3 barriers:
//  P1-serial: aLo reads; STAGE A0+A1(T+1)->nxt
//  bar; lgkm0; {bH(T) prefetch, QUAD00}; lgkm0; QUAD01
//  P3-serial: aHi reads
//  bar; lgkm0; STAGE B0(T+2)->cur; QUAD10
//  P4-serial: STAGE B1(T+2)->cur; WV(vmcnt(4))
//  bar(publish); {bL(T+1) prefetch from nxt, QUAD11}
#define TILE_N(BU, T, DOA, DOB, WV, DOPF) do { \
  _Pragma("unroll") for (int m_ = 0; m_ < 4; ++m_) { \
    aR0[m_] = LDA(BU, 0, m_, 0); aR1[m_] = LDA(BU, 0, m_, 1); } \
  if (DOA) { STAGE((BU) ^ 1, 0, gA, 0, (T) + 1); \
             STAGE((BU) ^ 1, 0, gA, 1, (T) + 1); } \
  SBAR; \
  LGKM0_FENCE; \
  __builtin_amdgcn_s_setprio(1); \
  _Pragma("unroll") for (int n_ = 0; n_ < 2; ++n_) { \
    bH0[n_] = LDB(BU, 1, n_, 0); bH1[n_] = LDB(BU, 1, n_, 1); } \
  QUAD(0, 0, bL0, bL1); \
  __builtin_amdgcn_s_setprio(0); \
  LGKM0_FENCE; \
  __builtin_amdgcn_s_setprio(1); \
  QUAD(0, 1, bH0, bH1); \
  __builtin_amdgcn_s_setprio(0); \
  _Pragma("unroll") for (int m_ = 0; m_ < 4; ++m_) { \
    aR0[m_] = LDA(BU, 1, m_, 0); aR1[m_] = LDA(BU, 1, m_, 1); } \
  SBAR; \
  LGKM0_FENCE; \
  if (DOB) STAGE(BU, 16384, gB, 0, (T) + 2); \
  __builtin_amdgcn_s_setprio(1); \
  QUAD(1, 0, bL0, bL1); \
  __builtin_amdgcn_s_setprio(0); \
  if (DOB) STAGE(BU, 16384, gB, 1, (T) + 2); \
  WV; \
  SBAR; \
  __builtin_amdgcn_s_setprio(1); \
  if (DOPF) { \
    _Pragma("unroll") for (int n_ = 0; n_ < 2; ++n_) { \
      bL0[n_] = LDB((BU) ^ 1, 0, n_, 0); bL1[n_] = LDB((BU) ^ 1, 0, n_, 1); } } \
  QUAD(1, 1, bH0, bH1); \
  __builtin_amdgcn_s_setprio(0); \
} while (0)

__global__ __launch_bounds__(512, 2) void k_gemm12(
    const unsigned short* __restrict__ A,   // [8192][8192] bf16 (permuted)
    const unsigned short* __restrict__ Bw,  // [2048][8192] bf16
    const float* __restrict__ bias,         // [2048]
    float* __restrict__ C) {                // [8192][2048] fp32
  __shared__ unsigned short sm[2 * 32768];  // 128 KiB
  unsigned short* smu = sm;
  const char* smb = (const char*)sm;

  const int tid  = threadIdx.x;
  const int lane = tid & 63;
  const int wave = tid >> 6;
  const int wr = wave >> 2;              // 0..1 -> 128-row half
  const int wc = wave & 3;               // 0..3 -> 64-col slice
  // XCD-grouped map (r10-verified: FETCH 540->197 MB)
  const int g  = blockIdx.x & 7;
  const int bm = g * 4 + ((blockIdx.x >> 3) & 3);  // 0..31
  const int bn = blockIdx.x >> 5;                  // 0..7

  const unsigned short* gA = A  + (size_t)bm * 256 * K_TOT;
  const unsigned short* gB = Bw + (size_t)bn * 256 * K_TOT;

  // staging address precompute (chunk ci = round*512 + tid; 8 slots/row)
  const int row0 = tid >> 3;
  const int sl0  = (((tid & 7) ^ (row0 & 7)) << 3);  // element offset of 16B slot
  const int row1 = (512 + tid) >> 3;
  const int sl1  = ((((512 + tid) & 7) ^ (row1 & 7)) << 3);

  // ds_read address precompute: byte col = (kk*64 | hi16*16) ^ ((lane&7)<<4)
  const int l15 = lane & 15;
  int colsw[2];
  colsw[0] = (((lane >> 4) << 4)) ^ ((lane & 7) << 4);
  colsw[1] = (64 | ((lane >> 4) << 4)) ^ ((lane & 7) << 4);
  const int aBase = (wr * 128 + l15) * 128;
  const int bBase = (wc * 64 + l15) * 128;

  f32x4 acc[8][4];
#pragma unroll
  for (int i = 0; i < 8; ++i)
#pragma unroll
    for (int j = 0; j < 4; ++j) {
      acc[i][j][0] = 0.f; acc[i][j][1] = 0.f; acc[i][j][2] = 0.f; acc[i][j][3] = 0.f;
    }
  bf16x8 aR0[4], aR1[4], bL0[2], bL1[2], bH0[2], bH1[2];

  // prologue: A(0),B(0)->buf0; B(1)->buf1; drain; publish; pre-read bL(0)
  STAGE(0, 0,     gA, 0, 0);
  STAGE(0, 0,     gA, 1, 0);
  STAGE(0, 16384, gB, 0, 0);
  STAGE(0, 16384, gB, 1, 0);
  STAGE(1, 16384, gB, 0, 1);
  STAGE(1, 16384, gB, 1, 1);
  VMW0;
  SBAR;
#pragma unroll
  for (int n_ = 0; n_ < 2; ++n_) {
    bL0[n_] = LDB(0, 0, n_, 0); bL1[n_] = LDB(0, 0, n_, 1);
  }

  for (int t = 0; t < 124; t += 2) {   // tiles 0..123
    TILE_N(0, t,     true, true, VMW4, true);
    TILE_N(1, t + 1, true, true, VMW4, true);
  }
  TILE_N(0, 124, true,  true,  VMW4, true);
  TILE_N(1, 125, true,  true,  VMW4, true);
  TILE_N(0, 126, true,  false, VMW0, true);   // drain all; prefetch bL(127)
  TILE_N(1, 127, false, false, VMWN, false);  // last: nothing staged

  // epilogue: C/D layout col = lane&15, row = (lane>>4)*4 + j
  const int crow0 = bm * 256 + wr * 128 + ((lane >> 4) << 2);
  const int ccol0 = bn * 256 + wc * 64 + l15;
  float bv[4];
#pragma unroll
  for (int n = 0; n < 4; ++n) bv[n] = bias[ccol0 + n * 16];
#pragma unroll
  for (int mi = 0; mi < 8; ++mi)
#pragma unroll
    for (int ni = 0; ni < 4; ++ni) {
      const int r = crow0 + mi * 16;
      const int c = ccol0 + ni * 16;
#pragma unroll
      for (int j = 0; j < 4; ++j)
        C[(size_t)(r + j) * N_OUT + c] = acc[mi][ni][j] + bv[ni];
    }
}

// -------- fallback: fp32 tiled GEMM with inline permutation (ws too small) ----
__global__ __launch_bounds__(256) void k_gemm_fallback(
    const float* __restrict__ W, const float* __restrict__ FW,
    const float* __restrict__ bias, const int* __restrict__ s1v,
    const int* __restrict__ s2v, float* __restrict__ C) {
  __shared__ float As[64][33];
  __shared__ float Bs[64][33];
  const int tid = threadIdx.x;
  const int tx = tid & 15, ty = tid >> 4;
  const int bm = blockIdx.x & 127;
  const int bn = blockIdx.x >> 7;
  float acc[4][4] = {{0.f}};
  for (int k0 = 0; k0 < K_TOT; k0 += 32) {
#pragma unroll
    for (int i = 0; i < 8; ++i) {
      int idx = i * 256 + tid;
      int rr = idx >> 5, cc = idx & 31;
      int grow = bm * 64 + rr;
      int gk = k0 + cc;
      int blkr = gk >> 11, within = gk & 2047;
      int s1 = s1v[grow] != 0, s2 = s2v[grow] != 0;
      int pr = perm_src(blkr, s1, s2);
      As[rr][cc] = W[(size_t)grow * K_TOT + (size_t)pr * 2048 + within];
      Bs[rr][cc] = FW[(size_t)(bn * 64 + rr) * K_TOT + gk];
    }
    __syncthreads();
#pragma unroll 8
    for (int kk = 0; kk < 32; ++kk) {
      float a[4], b[4];
#pragma unroll
      for (int i = 0; i < 4; ++i) a[i] = As[ty * 4 + i][kk];
#pragma unroll
      for (int j = 0; j < 4; ++j) b[j] = Bs[tx * 4 + j][kk];
#pragma unroll
      for (int i = 0; i < 4; ++i)
#pragma unroll
        for (int j = 0; j < 4; ++j) acc[i][j] += a[i] * b[j];
    }
    __syncthreads();
  }
#pragma unroll
  for (int i = 0; i < 4; ++i)
#pragma unroll
    for (int j = 0; j < 4; ++j) {
      int r = bm * 64 + ty * 4 + i, c = bn * 64 + tx * 4 + j;
      C[(size_t)r * N_OUT + c] = acc[i][j] + bias[c];
    }
}

extern "C" void kernel_launch(void* const* d_in, const int* in_sizes, int n_in,
                              void* d_out, int out_size, void* d_ws, size_t ws_size,
                              hipStream_t stream) {
  const float* weight = (const float*)d_in[0];  // [8192][8192]
  const float* fc_w   = (const float*)d_in[1];  // [2048][8192]
  const float* fc_b   = (const float*)d_in[2];  // [2048]
  const int*   swap1  = (const int*)d_in[3];    // [8192]
  const int*   swap2  = (const int*)d_in[4];    // [8192]
  float* out = (float*)d_out;

  const size_t xbf_bytes = (size_t)B_ROWS * K_TOT * 2;  // 128 MB
  const size_t wbf_bytes = (size_t)N_OUT * K_TOT * 2;   //  32 MB
  if (ws_size >= xbf_bytes + wbf_bytes) {
    unsigned short* xbf = (unsigned short*)d_ws;
    unsigned short* wbf = (unsigned short*)((char*)d_ws + xbf_bytes);
    k_prep<<<B_ROWS * 4 + (N_OUT * K_TOT) / 2048, 256, 0, stream>>>(
        weight, swap1, swap2, fc_w, xbf, wbf);
    k_gemm12<<<32 * 8, 512, 0, stream>>>(xbf, wbf, fc_b, out);
  } else {
    k_gemm_fallback<<<128 * 32, 256, 0, stream>>>(weight, fc_w, fc_b, swap1,
                                                  swap2, out);
  }
}

// Round 15
// 281.247 us; speedup vs baseline: 1.0071x; 1.0071x over previous
//
#include <hip/hip_runtime.h>
#include <hip/hip_bf16.h>
#include <stdint.h>

// out[b, n] = sum_k weight[b, perm(k)] * fc_w[n, k] + fc_b[n]
// FINAL (round-15 = round-13 revert, best measured: 280.98us total, GEMM
// 209.5us @ MfmaUtil 60.4%). Split architecture:
//  - k_prep: fold per-row block permutation + fp32->bf16 of weight (128MB)
//    and fc_w (32MB) into d_ws, one launch, ~58us (stream-bound).
//  - k_gemm11: 256^2-tile bf16 MFMA GEMM, BK=64, 8 waves; slot-XOR LDS
//    swizzle (conflicts=0); XCD-grouped block map (FETCH 540->197MB);
//    4-barrier K-tile schedule with zero-VGPR B-fragment prefetch pipeline
//    (bH(t) reads inside P1's MFMA cluster, bL(t+1) reads inside P4's MFMA
//    cluster after the early publish barrier); counted vmcnt(4); setprio.
// r14's 3-barrier variant measured neutral-to-worse (212.5us) -> reverted.
// Hazard trace for this schedule: see round-11 journal; all WAR pairs have
// >=2-barrier separation + lgkm0 drains, RAW covered by vmcnt(4)+publish.

using f32x4   = __attribute__((ext_vector_type(4))) float;
using bf16x8  = __attribute__((ext_vector_type(8))) __bf16;
using ushort8 = __attribute__((ext_vector_type(8))) unsigned short;

#define B_ROWS 8192
#define K_TOT  8192
#define N_OUT  2048
#define BK     64
#define NT     (K_TOT / BK)  // 128 K-tiles

__device__ __forceinline__ unsigned short f2bf(float f) {
  union { float f; unsigned int u; } v;
  v.f = f;
  unsigned int r = v.u + 0x7FFFu + ((v.u >> 16) & 1u);  // RNE
  return (unsigned short)(r >> 16);
}

__device__ __forceinline__ int perm_src(int r, int s1, int s2) {
  int mid = s1 ? 1 : 2;
  return (r == 0) ? 0
       : (r == 1) ? (s1 ? 2 : 1)
       : (r == 2) ? (s2 ? 3 : mid)
                  : (s2 ? mid : 3);
}

// -------- prep (merged): permute+convert weight; convert fc_w --------
__global__ __launch_bounds__(256) void k_prep(
    const float* __restrict__ w, const int* __restrict__ s1v,
    const int* __restrict__ s2v, const float* __restrict__ fw,
    unsigned short* __restrict__ xbf, unsigned short* __restrict__ wbf) {
  const int blk = blockIdx.x;
  const float* src;
  unsigned short* dst;
  if (blk < B_ROWS * 4) {
    const int b = blk >> 2, r = blk & 3;
    const int s1 = s1v[b] != 0, s2 = s2v[b] != 0;
    const int pr = perm_src(r, s1, s2);
    src = w + (size_t)b * K_TOT + (size_t)pr * 2048 + threadIdx.x * 8;
    dst = xbf + (size_t)b * K_TOT + (size_t)r * 2048 + threadIdx.x * 8;
  } else {
    const size_t base = ((size_t)(blk - B_ROWS * 4) * 256 + threadIdx.x) * 8;
    src = fw + base;
    dst = wbf + base;
  }
  f32x4 v0 = *(const f32x4*)src;
  f32x4 v1 = *(const f32x4*)(src + 4);
  ushort8 o;
#pragma unroll
  for (int j = 0; j < 4; ++j) o[j] = f2bf(v0[j]);
#pragma unroll
  for (int j = 0; j < 4; ++j) o[4 + j] = f2bf(v1[j]);
  *(ushort8*)dst = o;
}

// -------- GEMM --------
__device__ __forceinline__ void gload16(const unsigned short* g,
                                        const unsigned short* l) {
  __builtin_amdgcn_global_load_lds(
      (__attribute__((address_space(1))) void*)(uintptr_t)(const void*)g,
      (__attribute__((address_space(3))) void*)(unsigned int)(uintptr_t)(const void*)l,
      16, 0, 0);
}

#define VMW4 asm volatile("s_waitcnt vmcnt(4)" ::: "memory")
#define VMW0 asm volatile("s_waitcnt vmcnt(0)" ::: "memory")
#define VMWN ((void)0)
#define SBAR asm volatile("s_barrier" ::: "memory")
#define LGKM0_FENCE do { \
    asm volatile("s_waitcnt lgkmcnt(0)" ::: "memory"); \
    __builtin_amdgcn_sched_barrier(0); } while (0)

#define LDA(BU, MH, M, KKI) \
  (*(const bf16x8*)(smb + (BU)*65536 + aBase + ((MH)*64 + (M)*16)*128 + colsw[KKI]))
#define LDB(BU, NH, N, KKI) \
  (*(const bf16x8*)(smb + (BU)*65536 + 32768 + bBase + ((NH)*32 + (N)*16)*128 + colsw[KKI]))

// one half-tile (128 rows x 64 cols) = 2 global_load_lds x 512 threads
#define STAGE(BU, OPL, GOP, H, T) do { \
  gload16((GOP) + (size_t)((H)*128 + row0) * K_TOT + (size_t)(T)*BK + sl0, \
          smu + (BU)*32768 + (OPL) + (H)*8192 + tid*8); \
  gload16((GOP) + (size_t)((H)*128 + row1) * K_TOT + (size_t)(T)*BK + sl1, \
          smu + (BU)*32768 + (OPL) + (H)*8192 + 4096 + tid*8); \
} while (0)

#define QUAD(MH, NH, B0A, B1A) do { \
  _Pragma("unroll") for (int m_ = 0; m_ < 4; ++m_) \
    _Pragma("unroll") for (int n_ = 0; n_ < 2; ++n_) { \
      acc[(MH)*4+m_][(NH)*2+n_] = __builtin_amdgcn_mfma_f32_16x16x32_bf16( \
          aR0[m_], B0A[n_], acc[(MH)*4+m_][(NH)*2+n_], 0, 0, 0); \
      acc[(MH)*4+m_][(NH)*2+n_] = __builtin_amdgcn_mfma_f32_16x16x32_bf16( \
          aR1[m_], B1A[n_], acc[(MH)*4+m_][(NH)*2+n_], 0, 0, 0); \
    } \
} while (0)

// Per K-tile, 4 barriers. Phase layout:
//  P1: serial{read aLo(T); stage A0(T+1)->nxt}; bar; lgkm0;
//      MFMA aLo x bL  ||  prefetch bH(T)
//  P2: serial{stage A1(T+1)}; bar; lgkm0; MFMA aLo x bH
//  P3: serial{read aHi(T); stage B0(T+2)->cur}; bar; lgkm0; MFMA aHi x bL
//  P4: serial{stage B1(T+2)}; WV(vmcnt(4)); bar(publish);
//      MFMA aHi x bH  ||  prefetch bL(T+1) from nxt
#define TILE_N(BU, T, DOA, DOB, WV, DOPF) do { \
  _Pragma("unroll") for (int m_ = 0; m_ < 4; ++m_) { \
    aR0[m_] = LDA(BU, 0, m_, 0); aR1[m_] = LDA(BU, 0, m_, 1); } \
  if (DOA) STAGE((BU) ^ 1, 0, gA, 0, (T) + 1); \
  SBAR; \
  LGKM0_FENCE; \
  __builtin_amdgcn_s_setprio(1); \
  _Pragma("unroll") for (int n_ = 0; n_ < 2; ++n_) { \
    bH0[n_] = LDB(BU, 1, n_, 0); bH1[n_] = LDB(BU, 1, n_, 1); } \
  QUAD(0, 0, bL0, bL1); \
  __builtin_amdgcn_s_setprio(0); \
  if (DOA) STAGE((BU) ^ 1, 0, gA, 1, (T) + 1); \
  SBAR; \
  LGKM0_FENCE; \
  __builtin_amdgcn_s_setprio(1); \
  QUAD(0, 1, bH0, bH1); \
  __builtin_amdgcn_s_setprio(0); \
  _Pragma("unroll") for (int m_ = 0; m_ < 4; ++m_) { \
    aR0[m_] = LDA(BU, 1, m_, 0); aR1[m_] = LDA(BU, 1, m_, 1); } \
  if (DOB) STAGE(BU, 16384, gB, 0, (T) + 2); \
  SBAR; \
  LGKM0_FENCE; \
  __builtin_amdgcn_s_setprio(1); \
  QUAD(1, 0, bL0, bL1); \
  __builtin_amdgcn_s_setprio(0); \
  if (DOB) STAGE(BU, 16384, gB, 1, (T) + 2); \
  WV; \
  SBAR; \
  __builtin_amdgcn_s_setprio(1); \
  if (DOPF) { \
    _Pragma("unroll") for (int n_ = 0; n_ < 2; ++n_) { \
      bL0[n_] = LDB((BU) ^ 1, 0, n_, 0); bL1[n_] = LDB((BU) ^ 1, 0, n_, 1); } } \
  QUAD(1, 1, bH0, bH1); \
  __builtin_amdgcn_s_setprio(0); \
} while (0)

__global__ __launch_bounds__(512, 2) void k_gemm11(
    const unsigned short* __restrict__ A,   // [8192][8192] bf16 (permuted)
    const unsigned short* __restrict__ Bw,  // [2048][8192] bf16
    const float* __restrict__ bias,         // [2048]
    float* __restrict__ C) {                // [8192][2048] fp32
  __shared__ unsigned short sm[2 * 32768];  // 128 KiB
  unsigned short* smu = sm;
  const char* smb = (const char*)sm;

  const int tid  = threadIdx.x;
  const int lane = tid & 63;
  const int wave = tid >> 6;
  const int wr = wave >> 2;              // 0..1 -> 128-row half
  const int wc = wave & 3;               // 0..3 -> 64-col slice
  // XCD-grouped map (r10-verified: FETCH 540->197 MB)
  const int g  = blockIdx.x & 7;
  const int bm = g * 4 + ((blockIdx.x >> 3) & 3);  // 0..31
  const int bn = blockIdx.x >> 5;                  // 0..7

  const unsigned short* gA = A  + (size_t)bm * 256 * K_TOT;
  const unsigned short* gB = Bw + (size_t)bn * 256 * K_TOT;

  // staging address precompute (chunk ci = round*512 + tid; 8 slots/row)
  const int row0 = tid >> 3;
  const int sl0  = (((tid & 7) ^ (row0 & 7)) << 3);  // element offset of 16B slot
  const int row1 = (512 + tid) >> 3;
  const int sl1  = ((((512 + tid) & 7) ^ (row1 & 7)) << 3);

  // ds_read address precompute: byte col = (kk*64 | hi16*16) ^ ((lane&7)<<4)
  const int l15 = lane & 15;
  int colsw[2];
  colsw[0] = (((lane >> 4) << 4)) ^ ((lane & 7) << 4);
  colsw[1] = (64 | ((lane >> 4) << 4)) ^ ((lane & 7) << 4);
  const int aBase = (wr * 128 + l15) * 128;
  const int bBase = (wc * 64 + l15) * 128;

  f32x4 acc[8][4];
#pragma unroll
  for (int i = 0; i < 8; ++i)
#pragma unroll
    for (int j = 0; j < 4; ++j) {
      acc[i][j][0] = 0.f; acc[i][j][1] = 0.f; acc[i][j][2] = 0.f; acc[i][j][3] = 0.f;
    }
  bf16x8 aR0[4], aR1[4], bL0[2], bL1[2], bH0[2], bH1[2];

  // prologue: A(0),B(0)->buf0; B(1)->buf1; drain; publish; pre-read bL(0)
  STAGE(0, 0,     gA, 0, 0);
  STAGE(0, 0,     gA, 1, 0);
  STAGE(0, 16384, gB, 0, 0);
  STAGE(0, 16384, gB, 1, 0);
  STAGE(1, 16384, gB, 0, 1);
  STAGE(1, 16384, gB, 1, 1);
  VMW0;
  SBAR;
#pragma unroll
  for (int n_ = 0; n_ < 2; ++n_) {
    bL0[n_] = LDB(0, 0, n_, 0); bL1[n_] = LDB(0, 0, n_, 1);
  }

  for (int t = 0; t < 124; t += 2) {   // tiles 0..123
    TILE_N(0, t,     true, true, VMW4, true);
    TILE_N(1, t + 1, true, true, VMW4, true);
  }
  TILE_N(0, 124, true,  true,  VMW4, true);
  TILE_N(1, 125, true,  true,  VMW4, true);
  TILE_N(0, 126, true,  false, VMW0, true);   // drain all; prefetch bL(127)
  TILE_N(1, 127, false, false, VMWN, false);  // last: nothing staged

  // epilogue: C/D layout col = lane&15, row = (lane>>4)*4 + j
  const int crow0 = bm * 256 + wr * 128 + ((lane >> 4) << 2);
  const int ccol0 = bn * 256 + wc * 64 + l15;
  float bv[4];
#pragma unroll
  for (int n = 0; n < 4; ++n) bv[n] = bias[ccol0 + n * 16];
#pragma unroll
  for (int mi = 0; mi < 8; ++mi)
#pragma unroll
    for (int ni = 0; ni < 4; ++ni) {
      const int r = crow0 + mi * 16;
      const int c = ccol0 + ni * 16;
#pragma unroll
      for (int j = 0; j < 4; ++j)
        C[(size_t)(r + j) * N_OUT + c] = acc[mi][ni][j] + bv[ni];
    }
}

// -------- fallback: fp32 tiled GEMM with inline permutation (ws too small) ----
__global__ __launch_bounds__(256) void k_gemm_fallback(
    const float* __restrict__ W, const float* __restrict__ FW,
    const float* __restrict__ bias, const int* __restrict__ s1v,
    const int* __restrict__ s2v, float* __restrict__ C) {
  __shared__ float As[64][33];
  __shared__ float Bs[64][33];
  const int tid = threadIdx.x;
  const int tx = tid & 15, ty = tid >> 4;
  const int bm = blockIdx.x & 127;
  const int bn = blockIdx.x >> 7;
  float acc[4][4] = {{0.f}};
  for (int k0 = 0; k0 < K_TOT; k0 += 32) {
#pragma unroll
    for (int i = 0; i < 8; ++i) {
      int idx = i * 256 + tid;
      int rr = idx >> 5, cc = idx & 31;
      int grow = bm * 64 + rr;
      int gk = k0 + cc;
      int blkr = gk >> 11, within = gk & 2047;
      int s1 = s1v[grow] != 0, s2 = s2v[grow] != 0;
      int pr = perm_src(blkr, s1, s2);
      As[rr][cc] = W[(size_t)grow * K_TOT + (size_t)pr * 2048 + within];
      Bs[rr][cc] = FW[(size_t)(bn * 64 + rr) * K_TOT + gk];
    }
    __syncthreads();
#pragma unroll 8
    for (int kk = 0; kk < 32; ++kk) {
      float a[4], b[4];
#pragma unroll
      for (int i = 0; i < 4; ++i) a[i] = As[ty * 4 + i][kk];
#pragma unroll
      for (int j = 0; j < 4; ++j) b[j] = Bs[tx * 4 + j][kk];
#pragma unroll
      for (int i = 0; i < 4; ++i)
#pragma unroll
        for (int j = 0; j < 4; ++j) acc[i][j] += a[i] * b[j];
    }
    __syncthreads();
  }
#pragma unroll
  for (int i = 0; i < 4; ++i)
#pragma unroll
    for (int j = 0; j < 4; ++j) {
      int r = bm * 64 + ty * 4 + i, c = bn * 64 + tx * 4 + j;
      C[(size_t)r * N_OUT + c] = acc[i][j] + bias[c];
    }
}

extern "C" void kernel_launch(void* const* d_in, const int* in_sizes, int n_in,
                              void* d_out, int out_size, void* d_ws, size_t ws_size,
                              hipStream_t stream) {
  const float* weight = (const float*)d_in[0];  // [8192][8192]
  const float* fc_w   = (const float*)d_in[1];  // [2048][8192]
  const float* fc_b   = (const float*)d_in[2];  // [2048]
  const int*   swap1  = (const int*)d_in[3];    // [8192]
  const int*   swap2  = (const int*)d_in[4];    // [8192]
  float* out = (float*)d_out;

  const size_t xbf_bytes = (size_t)B_ROWS * K_TOT * 2;  // 128 MB
  const size_t wbf_bytes = (size_t)N_OUT * K_TOT * 2;   //  32 MB
  if (ws_size >= xbf_bytes + wbf_bytes) {
    unsigned short* xbf = (unsigned short*)d_ws;
    unsigned short* wbf = (unsigned short*)((char*)d_ws + xbf_bytes);
    k_prep<<<B_ROWS * 4 + (N_OUT * K_TOT) / 2048, 256, 0, stream>>>(
        weight, swap1, swap2, fc_w, xbf, wbf);
    k_gemm11<<<32 * 8, 512, 0, stream>>>(xbf, wbf, fc_b, out);
  } else {
    k_gemm_fallback<<<128 * 32, 256, 0, stream>>>(weight, fc_w, fc_b, swap1,
                                                  swap2, out);
  }
}